// Round 12
// baseline (36.285 us; speedup 1.0000x reference)
//
#include <hip/hip_runtime.h>
#include <hip/hip_bf16.h>
#include <stdint.h>

// SVR polynomial-kernel prediction:
//   out[m] = sum_n alpha[n] * (1 + x_p[m].X[n])^4 + b
// m=16384, n=8192, d=64, all fp32 in/out.
// R12: amortize the 2-phase overhead + kill LDS-read duplication:
//   - phase = 256 cols (32KB staged, 2x32KB dbuf) -> 8 barriers total;
//     4x 64-col sub-chunks pipeline inside each phase barrier-free
//   - wave-owns-16-cols (MT=8): 2 ds_read_b128/wave/sub-chunk (was 8)
//     -> CU LDS-read 24.6K->6.1K cyc, below the 19.9K cyc matrix floor
//   - grid 512 = EXACTLY 2 blocks/CU at launch_bounds(256,2) -> R9's
//     residency-raggedness trap closed by construction
//   - ping-pong deferred epilogue across sub-chunks (statically unrolled)
// Proven pieces verbatim: pre-swizzled Xs + linear global_load_lds
// (rule 21), swizzled ds_read slot=(g^(rr&7)) / ((4+g)^(rr&7)),
// a4-prescaled Xs + a4 C-init, alpha prefetched one phase ahead,
// LDS cross-wave reduce (no atomics), partials+finalize.

typedef __attribute__((ext_vector_type(8))) short bf16x8;
typedef __attribute__((ext_vector_type(8))) unsigned short ushort8;
typedef __attribute__((ext_vector_type(4))) float f32x4;

#define MM 16384
#define NN 8192
#define DD 64
#define NSPLIT 4           // n-splits -> partial slices
#define PHASES 8           // 256-col phases per block
#define BM 128             // m-rows per block
#define MT 8               // m-tiles per wave (all rows)

__device__ __forceinline__ unsigned short f2bf(float f) {
    uint32_t u = __float_as_uint(f);
    uint32_t r = (u + 0x7FFFu + ((u >> 16) & 1u)) >> 16;  // RNE
    return (unsigned short)r;
}

__device__ __forceinline__ void gll16(const void* g, void* l) {
    __builtin_amdgcn_global_load_lds(
        (const __attribute__((address_space(1))) unsigned int*)g,
        (__attribute__((address_space(3))) unsigned int*)l, 16, 0, 0);
}

// xp -> xbf linear row-major [16384][64] bf16.
// X  -> Xs swizzled: element (n,k) at shorts:
//   (n>>6)*4096 + (n&63)*64 + ((k>>3) ^ (n&7))*8 + (k&7),  prescaled by a4[n].
// alpha4f[n] = alpha[n]^(1/4).
__global__ void convert_kernel(const float* __restrict__ xp,
                               const float* __restrict__ X,
                               const float* __restrict__ alpha,
                               unsigned short* __restrict__ xbf,
                               unsigned short* __restrict__ Xs,
                               float* __restrict__ alpha4f) {
    const int xp4 = MM * DD / 4;          // 262144 float4 units
    const int xu = NN * DD / 8;           // 65536 16B units
    const int tot = xp4 + xu;
    int tid0 = blockIdx.x * blockDim.x + threadIdx.x;
    if (tid0 < NN) alpha4f[tid0] = sqrtf(sqrtf(alpha[tid0]));
    int stride = gridDim.x * blockDim.x;
    for (int i = tid0; i < tot; i += stride) {
        if (i < xp4) {
            float4 v = ((const float4*)xp)[i];
            ushort4 o;
            o.x = f2bf(v.x); o.y = f2bf(v.y); o.z = f2bf(v.z); o.w = f2bf(v.w);
            *(ushort4*)(xbf + (size_t)i * 4) = o;
        } else {
            int u = i - xp4;
            int n = u >> 3;
            int slot = u & 7;
            float a4 = sqrtf(sqrtf(alpha[n]));
            float4 va = ((const float4*)X)[n * 16 + slot * 2];
            float4 vb = ((const float4*)X)[n * 16 + slot * 2 + 1];
            ushort8 o;
            o[0] = f2bf(va.x * a4); o[1] = f2bf(va.y * a4);
            o[2] = f2bf(va.z * a4); o[3] = f2bf(va.w * a4);
            o[4] = f2bf(vb.x * a4); o[5] = f2bf(vb.y * a4);
            o[6] = f2bf(vb.z * a4); o[7] = f2bf(vb.w * a4);
            size_t dst = (size_t)(n >> 6) * 4096 + (n & 63) * 64
                       + ((slot ^ (n & 7)) * 8);
            *(ushort8*)(Xs + dst) = o;
        }
    }
}

// Stage the 32KB of phase PP into LDS buffer (PP&1)
#define STAGE_PHASE(PP)                                                   \
    {                                                                     \
        const char* gb = (const char*)Xs                                  \
            + (size_t)(chunk0 + (PP) * 4) * 8192 + tid * 16;              \
        char* lbase = smem + ((PP) & 1) * 32768 + w * 1024;               \
        _Pragma("unroll")                                                 \
        for (int j = 0; j < 8; ++j)                                       \
            gll16(gb + j * 4096, lbase + j * 4096);                       \
    }

#define MFMA_SUB(accv, bb0, bb1, avv)                                     \
    {                                                                     \
        _Pragma("unroll")                                                 \
        for (int mt = 0; mt < MT; ++mt)                                   \
            accv[mt] = (f32x4){avv, avv, avv, avv};                       \
        _Pragma("unroll")                                                 \
        for (int mt = 0; mt < MT; ++mt)                                   \
            accv[mt] = __builtin_amdgcn_mfma_f32_16x16x32_bf16(           \
                a[mt][0], bb0, accv[mt], 0, 0, 0);                        \
        _Pragma("unroll")                                                 \
        for (int mt = 0; mt < MT; ++mt)                                   \
            accv[mt] = __builtin_amdgcn_mfma_f32_16x16x32_bf16(           \
                a[mt][1], bb1, accv[mt], 0, 0, 0);                        \
    }

#define EPILOGUE8(accv)                                                   \
    {                                                                     \
        _Pragma("unroll")                                                 \
        for (int mt = 0; mt < MT; ++mt)                                   \
            _Pragma("unroll")                                             \
            for (int i = 0; i < 4; ++i) {                                 \
                float t = accv[mt][i];                                    \
                float t2 = t * t;                                         \
                red[mt][i] = fmaf(t2, t2, red[mt][i]);                    \
            }                                                             \
    }

// Sub-chunk SC of the current phase: 2 ds_read + 16 MFMA into ACC_THIS,
// deferred epilogue of ACC_PREV (previous sub-chunk).
#define SUBC(SC, ACC_THIS, ACC_PREV, DOPREV)                              \
    {                                                                     \
        const char* rowp = smem + bufb + (SC) * 8192 + rr * 128;          \
        bf16x8 b0 = *(const bf16x8*)(rowp + ((g ^ (rr & 7)) * 16));       \
        bf16x8 b1 = *(const bf16x8*)(rowp + (((4 + g) ^ (rr & 7)) * 16)); \
        MFMA_SUB(ACC_THIS, b0, b1, av_c[SC]);                             \
        if (DOPREV) EPILOGUE8(ACC_PREV);                                  \
    }

__global__ __launch_bounds__(256, 2) void svr_main(
        const unsigned short* __restrict__ xbf,
        const unsigned short* __restrict__ Xs,
        const float* __restrict__ alpha4f,
        float* __restrict__ partials) {
    extern __shared__ char smem[];        // 2 x 32KB phase buffers
    const int tid  = threadIdx.x;
    const int lane = tid & 63;
    const int w    = tid >> 6;            // wave 0..3 owns cols [w*16, w*16+16)
    const int r    = lane & 15;           // A-row-in-tile / B-col-in-tile
    const int g    = lane >> 4;           // k-slice selector
    const int mgroup = blockIdx.x >> 2;   // 0..127
    const int ns     = blockIdx.x & 3;    // 0..3
    const int rr     = w * 16 + r;        // col within 64-col sub-chunk

    // A fragments: 8 m-tiles x 2 k-slices, register-resident
    bf16x8 a[MT][2];
#pragma unroll
    for (int mt = 0; mt < MT; ++mt)
#pragma unroll
        for (int ks = 0; ks < 2; ++ks)
            a[mt][ks] = *(const bf16x8*)(
                xbf + (size_t)(mgroup * BM + mt * 16 + r) * DD
                    + ks * 32 + g * 8);

    f32x4 red[MT];
#pragma unroll
    for (int mt = 0; mt < MT; ++mt) red[mt] = (f32x4){0.f, 0.f, 0.f, 0.f};

    const int chunk0 = ns * (PHASES * 4);   // 64-col chunk id base

    // prologue: stage phase 0; load alpha for phase 0
    STAGE_PHASE(0);
    float av_c[4], av_n[4];
#pragma unroll
    for (int sc = 0; sc < 4; ++sc)
        av_c[sc] = alpha4f[(chunk0 + sc) * 64 + rr];
    __syncthreads();

    f32x4 accE[MT], accO[MT];

#pragma unroll 1
    for (int P = 0; P < PHASES; ++P) {
        const int bufb = (P & 1) * 32768;
        if (P + 1 < PHASES) {
            STAGE_PHASE(P + 1);
#pragma unroll
            for (int sc = 0; sc < 4; ++sc)
                av_n[sc] = alpha4f[(chunk0 + (P + 1) * 4 + sc) * 64 + rr];
        }
        SUBC(0, accE, accO, (P > 0));
        SUBC(1, accO, accE, true);
        SUBC(2, accE, accO, true);
        SUBC(3, accO, accE, true);
        __syncthreads();
        if (P + 1 < PHASES) {
#pragma unroll
            for (int sc = 0; sc < 4; ++sc) av_c[sc] = av_n[sc];
        }
    }
    // trailing epilogue: final sub-chunk (parity odd -> accO)
    EPILOGUE8(accO);

    // 1) shuffle-reduce across the 16 column-lanes (r) within each wave
#pragma unroll
    for (int mt = 0; mt < MT; ++mt)
#pragma unroll
        for (int i = 0; i < 4; ++i) {
            float v = red[mt][i];
            v += __shfl_xor(v, 1);
            v += __shfl_xor(v, 2);
            v += __shfl_xor(v, 4);
            v += __shfl_xor(v, 8);
            red[mt][i] = v;
        }
    // 2) cross-wave combine via LDS (loop's final barrier already passed)
    float* sred = (float*)smem;           // 4 x 128 floats = 2KB
    if (r == 0) {
#pragma unroll
        for (int mt = 0; mt < MT; ++mt)
#pragma unroll
            for (int i = 0; i < 4; ++i)
                sred[w * BM + mt * 16 + g * 4 + i] = red[mt][i];
    }
    __syncthreads();
    if (tid < BM) {
        float s = sred[tid] + sred[BM + tid] + sred[2 * BM + tid]
                + sred[3 * BM + tid];
        partials[(size_t)ns * MM + mgroup * BM + tid] = s;
    }
}

__global__ void finalize_kernel(const float* __restrict__ partials,
                                const float* __restrict__ bbias,
                                float* __restrict__ out) {
    int m = blockIdx.x * blockDim.x + threadIdx.x;
    if (m < MM) {
        float s = bbias[0];
#pragma unroll
        for (int c = 0; c < NSPLIT; ++c) s += partials[(size_t)c * MM + m];
        out[m] = s;
    }
}

extern "C" void kernel_launch(void* const* d_in, const int* in_sizes, int n_in,
                              void* d_out, int out_size, void* d_ws, size_t ws_size,
                              hipStream_t stream) {
    const float* xp    = (const float*)d_in[0];
    const float* X     = (const float*)d_in[1];
    const float* alpha = (const float*)d_in[2];
    const float* b     = (const float*)d_in[3];
    float* out = (float*)d_out;

    // ws: xbf 2MB | Xs 1MB | alpha4f 32KB | partials 4*16384*4 = 256KB
    unsigned short* xbf = (unsigned short*)d_ws;
    unsigned short* Xs  = xbf + (size_t)MM * DD;
    float* alpha4f = (float*)(Xs + (size_t)NN * DD);
    float* partials = alpha4f + NN;

    hipLaunchKernelGGL(convert_kernel, dim3(1280), dim3(256), 0, stream,
                       xp, X, alpha, xbf, Xs, alpha4f);

    hipLaunchKernelGGL(svr_main, dim3(128 * NSPLIT), dim3(256), 65536, stream,
                       xbf, Xs, alpha4f, partials);

    hipLaunchKernelGGL(finalize_kernel, dim3(MM / 256), dim3(256), 0, stream,
                       partials, b, out);
}